// Round 6
// baseline (417.750 us; speedup 1.0000x reference)
//
#include <hip/hip_runtime.h>
#include <hip/hip_fp16.h>
#include <math.h>

#define N_NODES 50000
#define N_EDGES 1600000
#define D_INF   128
#define D_HID   64
#define BN_EPS  1e-5f
#define NB      196      // coarse bins, 256 nodes each (bin = dst >> 8)
#define BINCAP  8832     // per-bin staging cap (mean 8192, +7 sigma)
#define EPB     6250     // edges per binA block (256 blocks x 6250 = E)

// =================== phase A: bin edges by dst>>8 (coalesced) ==============
// 256 blocks: large per-(block,bin) segments (~32 entries = 256B) coalesce
// well; LDS-atomic histogram cost is occupancy-invariant (measured R4/R5).
// staged entry: hi32 = wm fp32 bits; lo32 = src(0..15) | dst_low(16..23)
__global__ __launch_bounds__(256) void k_binA(const float* __restrict__ wsc,
                                              const float* __restrict__ wfc,
                                              const int*   __restrict__ ei,
                                              const float* __restrict__ alpha,
                                              int* __restrict__ bin_cur,
                                              unsigned long long* __restrict__ binned) {
    __shared__ int hcnt[NB];
    __shared__ int hbase[NB];
    int t = threadIdx.x;
    int e0 = blockIdx.x * EPB;
    if (t < NB) hcnt[t] = 0;
    __syncthreads();
    for (int i = t; i < EPB; i += 256) {
        int d = ei[N_EDGES + e0 + i];
        atomicAdd(&hcnt[d >> 8], 1);
    }
    __syncthreads();
    if (t < NB) { hbase[t] = atomicAdd(&bin_cur[t], hcnt[t]); hcnt[t] = 0; }
    __syncthreads();
    float a = 1.0f / (1.0f + expf(-alpha[0]));
    for (int i = t; i < EPB; i += 256) {
        int e = e0 + i;
        int s = ei[e], d = ei[N_EDGES + e];
        float wm = fmaf(a, wsc[e] - wfc[e], wfc[e]);   // a*wsc + (1-a)*wfc
        int bin = d >> 8;
        int slot = atomicAdd(&hcnt[bin], 1);
        int gpos = hbase[bin] + slot;
        if (gpos < BINCAP) {
            unsigned long long ent =
                ((unsigned long long)__float_as_uint(wm) << 32)
                | (unsigned int)(s | ((d & 255) << 16));
            binned[(size_t)bin * BINCAP + gpos] = ent;
        }
    }
}

// ============ phase B1: per-bin node histogram -> row_ptr + dinv ===========
__global__ __launch_bounds__(256) void k_binB1(const int* __restrict__ bin_cur,
                                               const unsigned long long* __restrict__ binned,
                                               int*   __restrict__ row_ptr,
                                               float* __restrict__ dinv) {
    __shared__ int   sscan[256];
    __shared__ int   ncnt[256];
    __shared__ float ndeg[256];
    int t = threadIdx.x;
    int bin = blockIdx.x;
    int v = (t < NB) ? min(bin_cur[t], BINCAP) : 0;
    sscan[t] = v;
    ncnt[t] = 0; ndeg[t] = 0.0f;
    __syncthreads();
    for (int off = 1; off < 256; off <<= 1) {
        int u = (t >= off) ? sscan[t - off] : 0;
        __syncthreads(); sscan[t] += u; __syncthreads();
    }
    int incl = sscan[bin];
    int base = (bin == 0) ? 0 : sscan[bin - 1];
    int cnt  = incl - base;
    __syncthreads();
    const unsigned long long* mybin = binned + (size_t)bin * BINCAP;
    for (int i = t; i < cnt; i += 256) {
        unsigned long long ent = mybin[i];
        unsigned int lo = (unsigned int)ent;
        int nl = (lo >> 16) & 255;
        float wm = __uint_as_float((unsigned int)(ent >> 32));
        atomicAdd(&ncnt[nl], 1);
        atomicAdd(&ndeg[nl], wm);
    }
    __syncthreads();
    int node0 = bin << 8;
    int nnodes = min(256, N_NODES - node0);
    if (t < nnodes) dinv[node0 + t] = rsqrtf(1.0f + ndeg[t]);  // +1 self loop
    int c = ncnt[t];
    sscan[t] = c;
    __syncthreads();
    for (int off = 1; off < 256; off <<= 1) {
        int u = (t >= off) ? sscan[t - off] : 0;
        __syncthreads(); sscan[t] += u; __syncthreads();
    }
    if (t < nnodes) row_ptr[node0 + t] = base + sscan[t] - c;
    if (bin == NB - 1 && t == 0) row_ptr[N_NODES] = base + cnt;
}

// == phase B2: scatter into LDS segment, chunk-sort rows by src, coalesced ==
// entry = src:16 | fp16(wm*dinv[src]):16. Replaces B2 + separate k_sort:
// scattered stores go to LDS; global write is one contiguous segment.
__global__ __launch_bounds__(256) void k_binB2(const int* __restrict__ bin_cur,
                                               const unsigned long long* __restrict__ binned,
                                               const int*   __restrict__ row_ptr,
                                               const float* __restrict__ dinv,
                                               unsigned int* __restrict__ csr) {
    __shared__ unsigned int seg[BINCAP];   // 34.5 KB
    __shared__ int lbase[257];
    __shared__ int ncur[256];
    int t = threadIdx.x;
    int bin = blockIdx.x;
    int node0 = bin << 8;
    int nnodes = min(256, N_NODES - node0);
    int base = row_ptr[node0];
    for (int i = t; i <= nnodes; i += 256) lbase[i] = row_ptr[node0 + i] - base;
    ncur[t] = 0;
    __syncthreads();
    int cnt = min(bin_cur[bin], BINCAP);   // == lbase[nnodes]
    const unsigned long long* mybin = binned + (size_t)bin * BINCAP;
    for (int i = t; i < cnt; i += 256) {
        unsigned long long ent = mybin[i];
        unsigned int lo = (unsigned int)ent;
        int nl  = (lo >> 16) & 255;
        int src = lo & 0xFFFFu;
        float wm = __uint_as_float((unsigned int)(ent >> 32));
        float nrm = wm * dinv[src];
        int slot = atomicAdd(&ncur[nl], 1);
        unsigned short nh = __half_as_ushort(__float2half_rn(nrm));
        seg[lbase[nl] + slot] = (unsigned int)src | ((unsigned int)nh << 16);
    }
    __syncthreads();
    // per-row 64-chunk bitonic sort by src (gather L2-locality heuristic)
    int w = t >> 6, lane = t & 63;
    for (int n = w; n < nnodes; n += 4) {
        int rb = lbase[n], re = lbase[n + 1];
        for (int b = rb; b < re; b += 64) {
            int c0 = min(64, re - b);
            unsigned int my = 0xFFFFFFFFu;              // sentinel sorts last
            if (lane < c0) my = seg[b + lane];
            unsigned int v = (my << 16) | (my >> 16);   // src -> high bits
#pragma unroll
            for (int k = 2; k <= 64; k <<= 1) {
#pragma unroll
                for (int j = k >> 1; j > 0; j >>= 1) {
                    unsigned int o = __shfl_xor(v, j, 64);
                    bool keepmin = (((lane & j) == 0) == ((lane & k) == 0));
                    v = keepmin ? min(v, o) : max(v, o);
                }
            }
            if (lane < c0) seg[b + lane] = (v << 16) | (v >> 16);
        }
    }
    __syncthreads();
    for (int i = t; i < cnt; i += 256) csr[base + i] = seg[i];   // coalesced
}

// =================== GEMM1: [N,128]x[128,64] -> fp16 =======================
__global__ __launch_bounds__(256) void k_gemm1(const float* __restrict__ x,
                                               const float* __restrict__ W,
                                               __half* __restrict__ out) {
    __shared__ float sw[D_INF * D_HID];   // 32 KB
    __shared__ float sx[16 * D_INF];      // 8 KB
    int t = threadIdx.x;
    int row0 = blockIdx.x * 16;
#pragma unroll
    for (int j = 0; j < 32; ++j) sw[t + j * 256] = W[t + j * 256];
#pragma unroll
    for (int j = 0; j < 8; ++j) {
        int i = t + j * 256;
        int r = i >> 7, k = i & 127;
        sx[i] = x[(row0 + r) * D_INF + k];
    }
    __syncthreads();
    int c = t & 63, rg = (t >> 6) * 4;
    float a0 = 0, a1 = 0, a2 = 0, a3 = 0;
#pragma unroll 4
    for (int k = 0; k < D_INF; ++k) {
        float w = sw[k * D_HID + c];
        a0 = fmaf(sx[(rg + 0) * D_INF + k], w, a0);
        a1 = fmaf(sx[(rg + 1) * D_INF + k], w, a1);
        a2 = fmaf(sx[(rg + 2) * D_INF + k], w, a2);
        a3 = fmaf(sx[(rg + 3) * D_INF + k], w, a3);
    }
    out[(row0 + rg + 0) * D_HID + c] = __float2half_rn(a0);
    out[(row0 + rg + 1) * D_HID + c] = __float2half_rn(a1);
    out[(row0 + rg + 2) * D_HID + c] = __float2half_rn(a2);
    out[(row0 + rg + 3) * D_HID + c] = __float2half_rn(a3);
}

// ======= GEMM2 fused BN1+ReLU on fp32 input: [N,64]x[64,64] -> fp16 ========
__global__ __launch_bounds__(256) void k_gemm2_bn(const float* __restrict__ h,
                                                  const float* __restrict__ scale,
                                                  const float* __restrict__ shift,
                                                  const float* __restrict__ W,
                                                  __half* __restrict__ out) {
    __shared__ float sw[D_HID * D_HID];   // 16 KB
    __shared__ float sx[16 * D_HID];      // 4 KB
    int t = threadIdx.x;
    int row0 = blockIdx.x * 16;
#pragma unroll
    for (int j = 0; j < 16; ++j) sw[t + j * 256] = W[t + j * 256];
#pragma unroll
    for (int j = 0; j < 4; ++j) {
        int i = t + j * 256;
        int k = i & 63;
        sx[i] = fmaxf(0.0f, fmaf(h[row0 * D_HID + i], scale[k], shift[k]));
    }
    __syncthreads();
    int c = t & 63, rg = (t >> 6) * 4;
    float a0 = 0, a1 = 0, a2 = 0, a3 = 0;
#pragma unroll 4
    for (int k = 0; k < D_HID; ++k) {
        float w = sw[k * D_HID + c];
        a0 = fmaf(sx[(rg + 0) * D_HID + k], w, a0);
        a1 = fmaf(sx[(rg + 1) * D_HID + k], w, a1);
        a2 = fmaf(sx[(rg + 2) * D_HID + k], w, a2);
        a3 = fmaf(sx[(rg + 3) * D_HID + k], w, a3);
    }
    out[(row0 + rg + 0) * D_HID + c] = __float2half_rn(a0);
    out[(row0 + rg + 1) * D_HID + c] = __float2half_rn(a1);
    out[(row0 + rg + 2) * D_HID + c] = __float2half_rn(a2);
    out[(row0 + rg + 3) * D_HID + c] = __float2half_rn(a3);
}

// ==== gather: wave/node, lane=feature, packed CSR, prefolded norms =========
// out[d] = dd * ( sum_e nrm_e * h[s_e] + dd * h[d] ) + bias
__global__ __launch_bounds__(256) void k_gather(const __half* __restrict__ h16,
                                                const unsigned int* __restrict__ csr,
                                                const int*   __restrict__ row_ptr,
                                                const float* __restrict__ dinv,
                                                const float* __restrict__ bias,
                                                float* __restrict__ out) {
    int t = threadIdx.x;
    int node = blockIdx.x * 4 + (t >> 6);
    int lane = t & 63;
    int beg = row_ptr[node], end = row_ptr[node + 1];
    float dd = dinv[node];
    float acc = dd * __half2float(h16[node * D_HID + lane]);
    for (int b = beg; b < end; b += 64) {
        int c0 = min(64, end - b);
        unsigned int my = 0;
        if (lane < c0) my = csr[b + lane];
        int j = 0;
        for (; j + 3 < c0; j += 4) {
            unsigned int u0 = __shfl(my, j,     64);
            unsigned int u1 = __shfl(my, j + 1, 64);
            unsigned int u2 = __shfl(my, j + 2, 64);
            unsigned int u3 = __shfl(my, j + 3, 64);
            float v0 = __half2float(h16[(u0 & 0xFFFFu) * D_HID + lane]);
            float v1 = __half2float(h16[(u1 & 0xFFFFu) * D_HID + lane]);
            float v2 = __half2float(h16[(u2 & 0xFFFFu) * D_HID + lane]);
            float v3 = __half2float(h16[(u3 & 0xFFFFu) * D_HID + lane]);
            acc = fmaf(v0, __half2float(__ushort_as_half((unsigned short)(u0 >> 16))), acc);
            acc = fmaf(v1, __half2float(__ushort_as_half((unsigned short)(u1 >> 16))), acc);
            acc = fmaf(v2, __half2float(__ushort_as_half((unsigned short)(u2 >> 16))), acc);
            acc = fmaf(v3, __half2float(__ushort_as_half((unsigned short)(u3 >> 16))), acc);
        }
        for (; j < c0; ++j) {
            unsigned int u = __shfl(my, j, 64);
            float v = __half2float(h16[(u & 0xFFFFu) * D_HID + lane]);
            acc = fmaf(v, __half2float(__ushort_as_half((unsigned short)(u >> 16))), acc);
        }
    }
    out[node * D_HID + lane] = fmaf(acc, dd, bias[lane]);
}

// ======== BN stats: per-block partial col sums/sumsq (no atomics) ==========
__global__ __launch_bounds__(256) void k_bn_stats(const float* __restrict__ h,
                                                  float* __restrict__ part) {
    __shared__ float s1[256], s2[256];
    int t = threadIdx.x;
    int col = t & 63;
    int rend = min(N_NODES, (int)((blockIdx.x + 1) * 256));
    float sum = 0.0f, sq = 0.0f;
    for (int r = blockIdx.x * 256 + (t >> 6); r < rend; r += 4) {
        float v = h[r * D_HID + col];
        sum += v; sq += v * v;
    }
    s1[t] = sum; s2[t] = sq;
    __syncthreads();
    if (t < 64) {
        float a = s1[t] + s1[t + 64] + s1[t + 128] + s1[t + 192];
        float b = s2[t] + s2[t + 64] + s2[t + 128] + s2[t + 192];
        part[blockIdx.x * 128 + t]      = a;
        part[blockIdx.x * 128 + 64 + t] = b;
    }
}

// ================= BN finalize: reduce partials -> scale/shift =============
__global__ void k_bn_finalize(const float* __restrict__ part,
                              const float* __restrict__ gamma,
                              const float* __restrict__ beta,
                              float* __restrict__ scale,
                              float* __restrict__ shift) {
    int j = threadIdx.x;
    if (j >= D_HID) return;
    float sum = 0.0f, sq = 0.0f;
    for (int b = 0; b < NB; ++b) {
        sum += part[b * 128 + j];
        sq  += part[b * 128 + 64 + j];
    }
    const float invn = 1.0f / (float)N_NODES;
    float mean = sum * invn;
    float var  = sq * invn - mean * mean;   // biased, matches jnp.var
    float sc   = gamma[j] / sqrtf(var + BN_EPS);
    scale[j] = sc;
    shift[j] = beta[j] - mean * sc;
}

// =============== BN apply + ReLU (in place, float4 vectorized) =============
__global__ void k_bn_apply_relu(float4* __restrict__ h,
                                const float* __restrict__ scale,
                                const float* __restrict__ shift) {
    int idx = blockIdx.x * blockDim.x + threadIdx.x;
    if (idx >= N_NODES * D_HID / 4) return;
    int j = (idx & 15) * 4;
    float4 v = h[idx];
    v.x = fmaxf(0.0f, fmaf(v.x, scale[j],     shift[j]));
    v.y = fmaxf(0.0f, fmaf(v.y, scale[j + 1], shift[j + 1]));
    v.z = fmaxf(0.0f, fmaf(v.z, scale[j + 2], shift[j + 2]));
    v.w = fmaxf(0.0f, fmaf(v.w, scale[j + 3], shift[j + 3]));
    h[idx] = v;
}

extern "C" void kernel_launch(void* const* d_in, const int* in_sizes, int n_in,
                              void* d_out, int out_size, void* d_ws, size_t ws_size,
                              hipStream_t stream) {
    const float* x     = (const float*)d_in[0];
    const int*   ei_sc = (const int*)  d_in[1];   // [2*E] src then dst
    const float* w_sc  = (const float*)d_in[2];
    const float* w_fc  = (const float*)d_in[4];
    const float* alpha = (const float*)d_in[5];
    const float* W1    = (const float*)d_in[6];
    const float* b1    = (const float*)d_in[7];
    const float* W2    = (const float*)d_in[8];
    const float* b2    = (const float*)d_in[9];
    const float* g1    = (const float*)d_in[10];
    const float* be1   = (const float*)d_in[11];
    const float* g2    = (const float*)d_in[12];
    const float* be2   = (const float*)d_in[13];
    float* out = (float*)d_out;

    // ---- workspace layout (binned first for 8B alignment): ~40 MB
    unsigned long long* binned = (unsigned long long*)d_ws;      // NB*BINCAP u64
    int*   bin_cur = (int*)(binned + (size_t)NB * BINCAP);       // NB
    float* dinv    = (float*)(bin_cur + NB);                     // N
    int*   row_ptr = (int*)(dinv + N_NODES);                     // N+1
    unsigned int* csr = (unsigned int*)(row_ptr + N_NODES + 1);  // E
    __half* h16    = (__half*)(csr + N_EDGES);                   // N*64 halves
    float* agg     = (float*)(h16 + (size_t)N_NODES * D_HID);    // N*64
    float* part    = agg + (size_t)N_NODES * D_HID;              // NB*128
    float* bnss    = part + NB * 128;                            // 128: scale|shift

    const int TB  = 256;
    const int gV4 = (N_NODES * D_HID / 4 + TB - 1) / TB;         // 3125
    const int gW  = N_NODES / 4;                                 // 12500 (wave/node)
    const int gGM = N_NODES / 16;                                // 3125

    // ---- CSR build: bin -> (row_ptr, dinv) -> sorted packed csr
    hipMemsetAsync(bin_cur, 0, NB * sizeof(int), stream);
    k_binA <<<256, TB, 0, stream>>>(w_sc, w_fc, ei_sc, alpha, bin_cur, binned);
    k_binB1<<<NB,  TB, 0, stream>>>(bin_cur, binned, row_ptr, dinv);
    k_binB2<<<NB,  TB, 0, stream>>>(bin_cur, binned, row_ptr, dinv, csr);

    // ---- layer 1
    k_gemm1      <<<gGM, TB, 0, stream>>>(x, W1, h16);
    k_gather     <<<gW,  TB, 0, stream>>>(h16, csr, row_ptr, dinv, b1, agg);
    k_bn_stats   <<<NB,  TB, 0, stream>>>(agg, part);
    k_bn_finalize<<<1,   64, 0, stream>>>(part, g1, be1, bnss, bnss + 64);

    // ---- layer 2 (BN1+ReLU fused into GEMM2 input load)
    k_gemm2_bn   <<<gGM, TB, 0, stream>>>(agg, bnss, bnss + 64, W2, h16);
    k_gather     <<<gW,  TB, 0, stream>>>(h16, csr, row_ptr, dinv, b2, out);
    k_bn_stats   <<<NB,  TB, 0, stream>>>(out, part);
    k_bn_finalize<<<1,   64, 0, stream>>>(part, g2, be2, bnss, bnss + 64);
    k_bn_apply_relu<<<gV4, TB, 0, stream>>>((float4*)out, bnss, bnss + 64);
}

// Round 7
// 356.285 us; speedup vs baseline: 1.1725x; 1.1725x over previous
//
#include <hip/hip_runtime.h>
#include <hip/hip_fp16.h>
#include <math.h>

#define N_NODES 50000
#define N_EDGES 1600000
#define D_INF   128
#define D_HID   64
#define BN_EPS  1e-5f
#define NBINS   391      // fine bins, 128 nodes each (bin = dst >> 7)
#define BINCAP  4608     // per-bin cap (mean 4092, +8 sigma)
#define EPB     6250     // edges per binA block (256 blocks x 6250 = E)
#define NSTATS  196      // bn_stats blocks (256 rows each)

// =================== phase A: bin edges by dst>>7 (coalesced) ==============
// 256 blocks: per-(block,bin) segments ~16 entries (128B) write-coalesce ok;
// LDS-atomic histogram cost is occupancy-invariant (measured R4/R5).
// staged entry: hi32 = wm fp32 bits; lo32 = src(0..15) | dst_low7(16..22)
__global__ __launch_bounds__(256) void k_binA(const float* __restrict__ wsc,
                                              const float* __restrict__ wfc,
                                              const int*   __restrict__ ei,
                                              const float* __restrict__ alpha,
                                              int* __restrict__ bin_cur,
                                              unsigned long long* __restrict__ binned) {
    __shared__ int hcnt[NBINS];
    __shared__ int hbase[NBINS];
    int t = threadIdx.x;
    int e0 = blockIdx.x * EPB;
    for (int b = t; b < NBINS; b += 256) hcnt[b] = 0;
    __syncthreads();
    for (int i = t; i < EPB; i += 256) {
        int d = ei[N_EDGES + e0 + i];
        atomicAdd(&hcnt[d >> 7], 1);
    }
    __syncthreads();
    for (int b = t; b < NBINS; b += 256) {
        int c = hcnt[b];
        hbase[b] = c ? atomicAdd(&bin_cur[b], c) : 0;
        hcnt[b] = 0;
    }
    __syncthreads();
    float a = 1.0f / (1.0f + expf(-alpha[0]));
    for (int i = t; i < EPB; i += 256) {
        int e = e0 + i;
        int s = ei[e], d = ei[N_EDGES + e];
        float wm = fmaf(a, wsc[e] - wfc[e], wfc[e]);   // a*wsc + (1-a)*wfc
        int bin = d >> 7;
        int slot = atomicAdd(&hcnt[bin], 1);
        int gpos = hbase[bin] + slot;
        if (gpos < BINCAP) {
            unsigned long long ent =
                ((unsigned long long)__float_as_uint(wm) << 32)
                | (unsigned int)(s | ((d & 127) << 16));
            binned[(size_t)bin * BINCAP + gpos] = ent;
        }
    }
}

// =============== bin base offsets: one-block exclusive scan ================
__global__ __launch_bounds__(512) void k_binbase(const int* __restrict__ bin_cur,
                                                 int* __restrict__ bin_base) {
    __shared__ int s[512];
    int t = threadIdx.x;
    int v = (t < NBINS) ? min(bin_cur[t], BINCAP) : 0;
    s[t] = v;
    __syncthreads();
    for (int off = 1; off < 512; off <<= 1) {
        int u = (t >= off) ? s[t - off] : 0;
        __syncthreads(); s[t] += u; __syncthreads();
    }
    if (t < NBINS) bin_base[t] = s[t] - v;        // exclusive base
    if (t == NBINS - 1) bin_base[NBINS] = s[t];   // total (== E)
}

// ============ phase B1: per-bin node histogram -> row_ptr + dinv ===========
__global__ __launch_bounds__(256) void k_binB1(const int* __restrict__ bin_cur,
                                               const int* __restrict__ bin_base,
                                               const unsigned long long* __restrict__ binned,
                                               int*   __restrict__ row_ptr,
                                               float* __restrict__ dinv) {
    __shared__ int   ncnt[128];
    __shared__ float ndeg[128];
    __shared__ int   sscan[128];
    int t = threadIdx.x;
    int bin = blockIdx.x;
    if (t < 128) { ncnt[t] = 0; ndeg[t] = 0.0f; }
    __syncthreads();
    int base = bin_base[bin];
    int cnt  = min(bin_cur[bin], BINCAP);
    const unsigned long long* mybin = binned + (size_t)bin * BINCAP;
    for (int i = t; i < cnt; i += 256) {
        unsigned long long ent = mybin[i];
        unsigned int lo = (unsigned int)ent;
        int nl = (lo >> 16) & 127;
        float wm = __uint_as_float((unsigned int)(ent >> 32));
        atomicAdd(&ncnt[nl], 1);
        atomicAdd(&ndeg[nl], wm);
    }
    __syncthreads();
    int node0 = bin << 7;
    int nnodes = min(128, N_NODES - node0);
    if (t < nnodes) dinv[node0 + t] = rsqrtf(1.0f + ndeg[t]);  // +1 self loop
    if (t < 128) sscan[t] = ncnt[t];
    __syncthreads();
    for (int off = 1; off < 128; off <<= 1) {
        int u = (t >= off && t < 128) ? sscan[t - off] : 0;
        __syncthreads();
        if (t < 128) sscan[t] += u;
        __syncthreads();
    }
    if (t < nnodes) row_ptr[node0 + t] = base + sscan[t] - ncnt[t];
    if (bin == NBINS - 1 && t == 0) row_ptr[N_NODES] = base + cnt;
}

// ==== phase B2: fill packed CSR; entry = src:16 | fp16(wm*dinv[src]):16 ====
__global__ __launch_bounds__(256) void k_binB2(const int* __restrict__ bin_cur,
                                               const unsigned long long* __restrict__ binned,
                                               const int*   __restrict__ row_ptr,
                                               const float* __restrict__ dinv,
                                               unsigned int* __restrict__ csr) {
    __shared__ int ncur[128];
    __shared__ int lb[128];
    int t = threadIdx.x;
    int bin = blockIdx.x;
    int node0 = bin << 7;
    int nnodes = min(128, N_NODES - node0);
    if (t < 128) ncur[t] = 0;
    if (t < nnodes) lb[t] = row_ptr[node0 + t];
    __syncthreads();
    int cnt = min(bin_cur[bin], BINCAP);
    const unsigned long long* mybin = binned + (size_t)bin * BINCAP;
    for (int i = t; i < cnt; i += 256) {
        unsigned long long ent = mybin[i];
        unsigned int lo = (unsigned int)ent;
        int nl  = (lo >> 16) & 127;
        int src = lo & 0xFFFFu;
        float wm = __uint_as_float((unsigned int)(ent >> 32));
        float nrm = wm * dinv[src];
        int slot = atomicAdd(&ncur[nl], 1);
        unsigned short nh = __half_as_ushort(__float2half_rn(nrm));
        csr[lb[nl] + slot] = (unsigned int)src | ((unsigned int)nh << 16);
    }
}

// =================== GEMM1: [N,128]x[128,64] -> fp16 =======================
__global__ __launch_bounds__(256) void k_gemm1(const float* __restrict__ x,
                                               const float* __restrict__ W,
                                               __half* __restrict__ out) {
    __shared__ float sw[D_INF * D_HID];   // 32 KB
    __shared__ float sx[16 * D_INF];      // 8 KB
    int t = threadIdx.x;
    int row0 = blockIdx.x * 16;
#pragma unroll
    for (int j = 0; j < 32; ++j) sw[t + j * 256] = W[t + j * 256];
#pragma unroll
    for (int j = 0; j < 8; ++j) {
        int i = t + j * 256;
        int r = i >> 7, k = i & 127;
        sx[i] = x[(row0 + r) * D_INF + k];
    }
    __syncthreads();
    int c = t & 63, rg = (t >> 6) * 4;
    float a0 = 0, a1 = 0, a2 = 0, a3 = 0;
#pragma unroll 4
    for (int k = 0; k < D_INF; ++k) {
        float w = sw[k * D_HID + c];
        a0 = fmaf(sx[(rg + 0) * D_INF + k], w, a0);
        a1 = fmaf(sx[(rg + 1) * D_INF + k], w, a1);
        a2 = fmaf(sx[(rg + 2) * D_INF + k], w, a2);
        a3 = fmaf(sx[(rg + 3) * D_INF + k], w, a3);
    }
    out[(row0 + rg + 0) * D_HID + c] = __float2half_rn(a0);
    out[(row0 + rg + 1) * D_HID + c] = __float2half_rn(a1);
    out[(row0 + rg + 2) * D_HID + c] = __float2half_rn(a2);
    out[(row0 + rg + 3) * D_HID + c] = __float2half_rn(a3);
}

// ======= GEMM2 fused BN1+ReLU on fp32 input: [N,64]x[64,64] -> fp16 ========
__global__ __launch_bounds__(256) void k_gemm2_bn(const float* __restrict__ h,
                                                  const float* __restrict__ scale,
                                                  const float* __restrict__ shift,
                                                  const float* __restrict__ W,
                                                  __half* __restrict__ out) {
    __shared__ float sw[D_HID * D_HID];   // 16 KB
    __shared__ float sx[16 * D_HID];      // 4 KB
    int t = threadIdx.x;
    int row0 = blockIdx.x * 16;
#pragma unroll
    for (int j = 0; j < 16; ++j) sw[t + j * 256] = W[t + j * 256];
#pragma unroll
    for (int j = 0; j < 4; ++j) {
        int i = t + j * 256;
        int k = i & 63;
        sx[i] = fmaxf(0.0f, fmaf(h[row0 * D_HID + i], scale[k], shift[k]));
    }
    __syncthreads();
    int c = t & 63, rg = (t >> 6) * 4;
    float a0 = 0, a1 = 0, a2 = 0, a3 = 0;
#pragma unroll 4
    for (int k = 0; k < D_HID; ++k) {
        float w = sw[k * D_HID + c];
        a0 = fmaf(sx[(rg + 0) * D_HID + k], w, a0);
        a1 = fmaf(sx[(rg + 1) * D_HID + k], w, a1);
        a2 = fmaf(sx[(rg + 2) * D_HID + k], w, a2);
        a3 = fmaf(sx[(rg + 3) * D_HID + k], w, a3);
    }
    out[(row0 + rg + 0) * D_HID + c] = __float2half_rn(a0);
    out[(row0 + rg + 1) * D_HID + c] = __float2half_rn(a1);
    out[(row0 + rg + 2) * D_HID + c] = __float2half_rn(a2);
    out[(row0 + rg + 3) * D_HID + c] = __float2half_rn(a3);
}

// ==== gather: wave/node, lane=feature, packed CSR, prefolded norms =========
// out[d] = dd * ( sum_e nrm_e * h[s_e] + dd * h[d] ) + bias
__global__ __launch_bounds__(256) void k_gather(const __half* __restrict__ h16,
                                                const unsigned int* __restrict__ csr,
                                                const int*   __restrict__ row_ptr,
                                                const float* __restrict__ dinv,
                                                const float* __restrict__ bias,
                                                float* __restrict__ out) {
    int t = threadIdx.x;
    int node = blockIdx.x * 4 + (t >> 6);
    int lane = t & 63;
    int beg = row_ptr[node], end = row_ptr[node + 1];
    float dd = dinv[node];
    float acc = dd * __half2float(h16[node * D_HID + lane]);
    for (int b = beg; b < end; b += 64) {
        int c0 = min(64, end - b);
        unsigned int my = 0;
        if (lane < c0) my = csr[b + lane];
        int j = 0;
        for (; j + 7 < c0; j += 8) {   // 8-wide: 8 outstanding gathers
            unsigned int u0 = __shfl(my, j,     64);
            unsigned int u1 = __shfl(my, j + 1, 64);
            unsigned int u2 = __shfl(my, j + 2, 64);
            unsigned int u3 = __shfl(my, j + 3, 64);
            unsigned int u4 = __shfl(my, j + 4, 64);
            unsigned int u5 = __shfl(my, j + 5, 64);
            unsigned int u6 = __shfl(my, j + 6, 64);
            unsigned int u7 = __shfl(my, j + 7, 64);
            float v0 = __half2float(h16[(u0 & 0xFFFFu) * D_HID + lane]);
            float v1 = __half2float(h16[(u1 & 0xFFFFu) * D_HID + lane]);
            float v2 = __half2float(h16[(u2 & 0xFFFFu) * D_HID + lane]);
            float v3 = __half2float(h16[(u3 & 0xFFFFu) * D_HID + lane]);
            float v4 = __half2float(h16[(u4 & 0xFFFFu) * D_HID + lane]);
            float v5 = __half2float(h16[(u5 & 0xFFFFu) * D_HID + lane]);
            float v6 = __half2float(h16[(u6 & 0xFFFFu) * D_HID + lane]);
            float v7 = __half2float(h16[(u7 & 0xFFFFu) * D_HID + lane]);
            acc = fmaf(v0, __half2float(__ushort_as_half((unsigned short)(u0 >> 16))), acc);
            acc = fmaf(v1, __half2float(__ushort_as_half((unsigned short)(u1 >> 16))), acc);
            acc = fmaf(v2, __half2float(__ushort_as_half((unsigned short)(u2 >> 16))), acc);
            acc = fmaf(v3, __half2float(__ushort_as_half((unsigned short)(u3 >> 16))), acc);
            acc = fmaf(v4, __half2float(__ushort_as_half((unsigned short)(u4 >> 16))), acc);
            acc = fmaf(v5, __half2float(__ushort_as_half((unsigned short)(u5 >> 16))), acc);
            acc = fmaf(v6, __half2float(__ushort_as_half((unsigned short)(u6 >> 16))), acc);
            acc = fmaf(v7, __half2float(__ushort_as_half((unsigned short)(u7 >> 16))), acc);
        }
        for (; j < c0; ++j) {
            unsigned int u = __shfl(my, j, 64);
            float v = __half2float(h16[(u & 0xFFFFu) * D_HID + lane]);
            acc = fmaf(v, __half2float(__ushort_as_half((unsigned short)(u >> 16))), acc);
        }
    }
    out[node * D_HID + lane] = fmaf(acc, dd, bias[lane]);
}

// ======== BN stats: per-block partial col sums/sumsq (no atomics) ==========
__global__ __launch_bounds__(256) void k_bn_stats(const float* __restrict__ h,
                                                  float* __restrict__ part) {
    __shared__ float s1[256], s2[256];
    int t = threadIdx.x;
    int col = t & 63;
    int rend = min(N_NODES, (int)((blockIdx.x + 1) * 256));
    float sum = 0.0f, sq = 0.0f;
    for (int r = blockIdx.x * 256 + (t >> 6); r < rend; r += 4) {
        float v = h[r * D_HID + col];
        sum += v; sq += v * v;
    }
    s1[t] = sum; s2[t] = sq;
    __syncthreads();
    if (t < 64) {
        float a = s1[t] + s1[t + 64] + s1[t + 128] + s1[t + 192];
        float b = s2[t] + s2[t + 64] + s2[t + 128] + s2[t + 192];
        part[blockIdx.x * 128 + t]      = a;
        part[blockIdx.x * 128 + 64 + t] = b;
    }
}

// ================= BN finalize: reduce partials -> scale/shift =============
__global__ void k_bn_finalize(const float* __restrict__ part,
                              const float* __restrict__ gamma,
                              const float* __restrict__ beta,
                              float* __restrict__ scale,
                              float* __restrict__ shift) {
    int j = threadIdx.x;
    if (j >= D_HID) return;
    float sum = 0.0f, sq = 0.0f;
    for (int b = 0; b < NSTATS; ++b) {
        sum += part[b * 128 + j];
        sq  += part[b * 128 + 64 + j];
    }
    const float invn = 1.0f / (float)N_NODES;
    float mean = sum * invn;
    float var  = sq * invn - mean * mean;   // biased, matches jnp.var
    float sc   = gamma[j] / sqrtf(var + BN_EPS);
    scale[j] = sc;
    shift[j] = beta[j] - mean * sc;
}

// =============== BN apply + ReLU (in place, float4 vectorized) =============
__global__ void k_bn_apply_relu(float4* __restrict__ h,
                                const float* __restrict__ scale,
                                const float* __restrict__ shift) {
    int idx = blockIdx.x * blockDim.x + threadIdx.x;
    if (idx >= N_NODES * D_HID / 4) return;
    int j = (idx & 15) * 4;
    float4 v = h[idx];
    v.x = fmaxf(0.0f, fmaf(v.x, scale[j],     shift[j]));
    v.y = fmaxf(0.0f, fmaf(v.y, scale[j + 1], shift[j + 1]));
    v.z = fmaxf(0.0f, fmaf(v.z, scale[j + 2], shift[j + 2]));
    v.w = fmaxf(0.0f, fmaf(v.w, scale[j + 3], shift[j + 3]));
    h[idx] = v;
}

extern "C" void kernel_launch(void* const* d_in, const int* in_sizes, int n_in,
                              void* d_out, int out_size, void* d_ws, size_t ws_size,
                              hipStream_t stream) {
    const float* x     = (const float*)d_in[0];
    const int*   ei_sc = (const int*)  d_in[1];   // [2*E] src then dst
    const float* w_sc  = (const float*)d_in[2];
    const float* w_fc  = (const float*)d_in[4];
    const float* alpha = (const float*)d_in[5];
    const float* W1    = (const float*)d_in[6];
    const float* b1    = (const float*)d_in[7];
    const float* W2    = (const float*)d_in[8];
    const float* b2    = (const float*)d_in[9];
    const float* g1    = (const float*)d_in[10];
    const float* be1   = (const float*)d_in[11];
    const float* g2    = (const float*)d_in[12];
    const float* be2   = (const float*)d_in[13];
    float* out = (float*)d_out;

    // ---- workspace layout (binned first for 8B alignment): ~41 MB
    unsigned long long* binned = (unsigned long long*)d_ws;      // NBINS*BINCAP u64
    int*   bin_cur  = (int*)(binned + (size_t)NBINS * BINCAP);   // NBINS
    int*   bin_base = bin_cur + NBINS;                           // NBINS+1
    float* dinv     = (float*)(bin_base + NBINS + 1);            // N
    int*   row_ptr  = (int*)(dinv + N_NODES);                    // N+1
    unsigned int* csr = (unsigned int*)(row_ptr + N_NODES + 1);  // E
    __half* h16     = (__half*)(csr + N_EDGES);                  // N*64 halves
    float* agg      = (float*)(h16 + (size_t)N_NODES * D_HID);   // N*64
    float* part     = agg + (size_t)N_NODES * D_HID;             // NSTATS*128
    float* bnss     = part + NSTATS * 128;                       // 128: scale|shift

    const int TB  = 256;
    const int gV4 = (N_NODES * D_HID / 4 + TB - 1) / TB;         // 3125
    const int gW  = N_NODES / 4;                                 // 12500 (wave/node)
    const int gGM = N_NODES / 16;                                // 3125

    // ---- CSR build: binA -> base scan -> (row_ptr, dinv) -> packed csr
    hipMemsetAsync(bin_cur, 0, NBINS * sizeof(int), stream);
    k_binA   <<<256,   TB, 0, stream>>>(w_sc, w_fc, ei_sc, alpha, bin_cur, binned);
    k_binbase<<<1,    512, 0, stream>>>(bin_cur, bin_base);
    k_binB1  <<<NBINS, TB, 0, stream>>>(bin_cur, bin_base, binned, row_ptr, dinv);
    k_binB2  <<<NBINS, TB, 0, stream>>>(bin_cur, binned, row_ptr, dinv, csr);

    // ---- layer 1
    k_gemm1      <<<gGM, TB, 0, stream>>>(x, W1, h16);
    k_gather     <<<gW,  TB, 0, stream>>>(h16, csr, row_ptr, dinv, b1, agg);
    k_bn_stats   <<<NSTATS, TB, 0, stream>>>(agg, part);
    k_bn_finalize<<<1,   64, 0, stream>>>(part, g1, be1, bnss, bnss + 64);

    // ---- layer 2 (BN1+ReLU fused into GEMM2 input load)
    k_gemm2_bn   <<<gGM, TB, 0, stream>>>(agg, bnss, bnss + 64, W2, h16);
    k_gather     <<<gW,  TB, 0, stream>>>(h16, csr, row_ptr, dinv, b2, out);
    k_bn_stats   <<<NSTATS, TB, 0, stream>>>(out, part);
    k_bn_finalize<<<1,   64, 0, stream>>>(part, g2, be2, bnss, bnss + 64);
    k_bn_apply_relu<<<gV4, TB, 0, stream>>>((float4*)out, bnss, bnss + 64);
}